// Round 13
// baseline (8569.402 us; speedup 1.0000x reference)
//
#include <hip/hip_runtime.h>
#include <hip/hip_fp16.h>
#include <math.h>

// Problem dims (fixed)
#define T_SEQ 4096
#define DIN   64
#define DM    1024
#define G4    4096              // 4*DM gate rows
#define LSTRIDE_W ((size_t)G4 * DM)   // per-layer Wih/Whh stride
#define LSTRIDE_B ((size_t)G4)        // per-layer bias stride

#define SENT16 0xDEADu          // f16 sentinel: |h|<=1 never encodes 0xDEAD
#define SENT32 0xDEADDEADu

// Timed waits. Session lessons:
//  R15: fixed pacing only (closed-loop adaptive pacing diverges).
//  R18: sample ONCE; early probes miss and perturb the propagation.
//  R19: period scales with PUBLISHER COUNT (32 L0 / 64 L1 is optimal).
//  R20: publisher's post-B2 tail is free (hidden under stagers' sleep).
//  R22: S_RING=22 -> partial misses (FETCH 125->150MB), net +0.1-0.2ms win;
//       visibility tail sits near the 22-quantum sample point.
//  R23: bisect 22..28 at 25 (observation ~1950cy): if tail clears, bank
//       192cy/step with a clean protocol; else R22 is the optimum.
#define S_RING  25              // s_sleep(25) ~1600 cy: ring visibility wait
#define S_RETRY 6               // ~384 cy paced retry
#define S_HIST  8               // ~512 cy: L1 catch-up when L0 is behind

typedef unsigned long long u64;
typedef unsigned int u32;
typedef unsigned short u16;

// sleep + compiler memory fence (prevent hoisting atomic loads above it)
#define PAUSE(n) do { __builtin_amdgcn_s_sleep(n); asm volatile("" ::: "memory"); } while (0)

__device__ __forceinline__ float sigmoidf_(float x) {
    return 1.0f / (1.0f + __expf(-x));
}
__device__ __forceinline__ float tanhf_(float x) {
    float ax = fabsf(x);
    float e  = __expf(-2.0f * ax);
    float t  = (1.0f - e) / (1.0f + e);
    return copysignf(t, x);
}
__device__ __forceinline__ float lrelu_(float x) {
    return x > 0.0f ? x : 0.01f * x;
}

// pack two fp32 -> one u32 of two f16 (v_cvt_pkrtz_f16_f32)
__device__ __forceinline__ u32 pk2_(float x, float y) {
    typedef __fp16 hv2 __attribute__((ext_vector_type(2)));
    union { hv2 h; u32 u; } c;
    c.h = __builtin_amdgcn_cvt_pkrtz(x, y);
    return c.u;
}
// fused f16-pair dot-accumulate: acc += a.x*b.x + a.y*b.y
#if __has_builtin(__builtin_amdgcn_fdot2)
__device__ __forceinline__ float d2a_(u32 a, u32 b, float acc) {
    typedef __fp16 hv2 __attribute__((ext_vector_type(2)));
    union { u32 u; hv2 h; } ua, ub;
    ua.u = a; ub.u = b;
    return __builtin_amdgcn_fdot2(ua.h, ub.h, acc, false);
}
#else
__device__ __forceinline__ float d2a_(u32 a, u32 b, float acc) {
    union { u32 u; __half2 h; } ua, ub;
    ua.u = a; ub.u = b;
    float2 fa = __half22float2(ua.h);
    float2 fb = __half22float2(ub.h);
    return acc + fa.x * fb.x + fa.y * fb.y;
}
#endif
__device__ __forceinline__ float dot8a_(uint4 q, uint4 h, float acc) {
    acc = d2a_(q.x, h.x, acc);
    acc = d2a_(q.y, h.y, acc);
    acc = d2a_(q.z, h.z, acc);
    acc = d2a_(q.w, h.w, acc);
    return acc;
}
// any of the four f16 fields still the sentinel?
__device__ __forceinline__ bool has_sent_(u64 v) {
    return (((u32)v & 0xFFFFu) == SENT16) | ((((u32)v >> 16)) == SENT16) |
           (((u32)(v >> 32) & 0xFFFFu) == SENT16) | (((u32)(v >> 48)) == SENT16);
}

// ---------------------------------------------------------------------------
// K1: x[t,d] = leaky_relu(sum_k inp[t,k]*W1[d,k] + b1[d]);  grid=4096, block=256
// ---------------------------------------------------------------------------
__global__ __launch_bounds__(256) void k_input(const float* __restrict__ inp,
                                               const float* __restrict__ W1,
                                               const float* __restrict__ b1,
                                               float* __restrict__ x) {
    __shared__ float s_in[DIN];
    const int t   = blockIdx.x;
    const int tid = threadIdx.x;
    if (tid < DIN) s_in[tid] = inp[(size_t)t * DIN + tid];
    __syncthreads();
#pragma unroll
    for (int q = 0; q < 4; q++) {
        const int d = tid + q * 256;
        const float4* wr = (const float4*)(W1 + (size_t)d * DIN);
        float acc = 0.0f;
#pragma unroll
        for (int e = 0; e < 16; e++) {
            float4 w = wr[e];
            acc += w.x * s_in[e * 4 + 0] + w.y * s_in[e * 4 + 1] +
                   w.z * s_in[e * 4 + 2] + w.w * s_in[e * 4 + 3];
        }
        acc += b1[d];
        x[(size_t)t * DM + d] = lrelu_(acc);
    }
}

// ---------------------------------------------------------------------------
// K2: xg[m,n] = sum_k x[m,k]*Wih0[n,k] + (bih0[n]+bhh0[n])
// 128x128 tile, BK=16, 256 threads, 8x8 per thread.
// ---------------------------------------------------------------------------
__global__ __launch_bounds__(256) void k_gemm(const float* __restrict__ A,
                                              const float* __restrict__ B,
                                              const float* __restrict__ bih,
                                              const float* __restrict__ bhh,
                                              float* __restrict__ C) {
    const int K = DM;
    __shared__ float As[16][132];
    __shared__ float Bs[16][132];
    const int tid = threadIdx.x;
    const int m0 = blockIdx.y * 128, n0 = blockIdx.x * 128;
    const int tx = tid & 15, ty = tid >> 4;
    const int lr = tid >> 1;
    const int lc = (tid & 1) * 8;

    float acc[8][8] = {};
    const float4* ag = (const float4*)(A + (size_t)(m0 + lr) * K + lc);
    const float4* bg = (const float4*)(B + (size_t)(n0 + lr) * K + lc);

    for (int k0 = 0; k0 < K; k0 += 16) {
        float4 a0 = ag[0], a1 = ag[1];
        float4 b0 = bg[0], b1v = bg[1];
        ag += 4; bg += 4;
        __syncthreads();
        As[lc + 0][lr] = a0.x; As[lc + 1][lr] = a0.y; As[lc + 2][lr] = a0.z; As[lc + 3][lr] = a0.w;
        As[lc + 4][lr] = a1.x; As[lc + 5][lr] = a1.y; As[lc + 6][lr] = a1.z; As[lc + 7][lr] = a1.w;
        Bs[lc + 0][lr] = b0.x; Bs[lc + 1][lr] = b0.y; Bs[lc + 2][lr] = b0.z; Bs[lc + 3][lr] = b0.w;
        Bs[lc + 4][lr] = b1v.x; Bs[lc + 5][lr] = b1v.y; Bs[lc + 6][lr] = b1v.z; Bs[lc + 7][lr] = b1v.w;
        __syncthreads();
#pragma unroll
        for (int k = 0; k < 16; k++) {
            float a[8], b[8];
            *(float4*)&a[0] = *(const float4*)&As[k][ty * 8 + 0];
            *(float4*)&a[4] = *(const float4*)&As[k][ty * 8 + 4];
            *(float4*)&b[0] = *(const float4*)&Bs[k][tx * 8 + 0];
            *(float4*)&b[4] = *(const float4*)&Bs[k][tx * 8 + 4];
#pragma unroll
            for (int i = 0; i < 8; i++)
#pragma unroll
                for (int j = 0; j < 8; j++)
                    acc[i][j] += a[i] * b[j];
        }
    }
    float bj[8];
#pragma unroll
    for (int j = 0; j < 8; j++) {
        int n = n0 + tx * 8 + j;
        bj[j] = bih[n] + bhh[n];
    }
#pragma unroll
    for (int i = 0; i < 8; i++) {
        float4 v0, v1;
        v0.x = acc[i][0] + bj[0]; v0.y = acc[i][1] + bj[1];
        v0.z = acc[i][2] + bj[2]; v0.w = acc[i][3] + bj[3];
        v1.x = acc[i][4] + bj[4]; v1.y = acc[i][5] + bj[5];
        v1.z = acc[i][6] + bj[6]; v1.w = acc[i][7] + bj[7];
        float* cp = C + (size_t)(m0 + ty * 8 + i) * G4 + n0 + tx * 8;
        *(float4*)(cp + 0) = v0;
        *(float4*)(cp + 4) = v1;
    }
}

// ---------------------------------------------------------------------------
// K2b: sentinel-clear BOTH f16 histories (16 MB over the dead x buffer).
// ---------------------------------------------------------------------------
__global__ __launch_bounds__(256) void k_clear(u32* __restrict__ p) {
    uint4 v; v.x = SENT32; v.y = SENT32; v.z = SENT32; v.w = SENT32;
    ((uint4*)p)[(size_t)blockIdx.x * 256 + threadIdx.x] = v;
}

// ---------------------------------------------------------------------------
// K3: R23 = R22 structure (byte-exact R17 topology) with S_RING 22 -> 25,
// the final bisection point on the measured response curve
// (12 fail / 22 partial-miss / 28 clean / 40 clean-slow).
//   - 32 L0 WGs x 32 states, 64 L1 WGs x 16 states, 1024 threads each.
//   - ONE coalesced 64B/32B publish per WG per step; post-B2 tail hidden.
//   - 256 stager threads per WG; zero-gap rings: silent sleep -> sample
//     ONCE -> paced retries. L1 h0-read load-first with paced catch-up.
//   - 128 rows/WG, 8 threads/row, weights in 64 VGPRs, shfl_xor reduce.
// ---------------------------------------------------------------------------
__global__ __launch_bounds__(1024, 1) void k_scan(
        const float* __restrict__ xg,     // T x 4096 layer-0 preacts
        const float* __restrict__ Wih1,
        const float* __restrict__ Whh0,
        const float* __restrict__ Whh1,
        const float* __restrict__ bih1,
        const float* __restrict__ bhh1,
        u16* h0h,                         // [T][1024] f16 h0 history (sentinel)
        u16* h1h,                         // [T][1024] f16 h1 history (sentinel)
        float* __restrict__ out) {
    const int tid   = threadIdx.x;
    const int rowid = tid >> 3;           // 0..127: row handled by this thread
    const int c     = tid & 7;            // k-chunk within row
    const bool isL0 = (blockIdx.x < 32);

    __shared__ uint4 h0st[2][128];        // staged h0 row (f16), parity dbuf
    __shared__ uint4 h1st[2][128];        // staged h1 row (f16), parity dbuf
    __shared__ __align__(16) float pre[128];  // row preacts for gate gather

    if (isL0) {
        // =============== Layer-0: 32 WGs x 32 states ===============
        const int w = blockIdx.x;                 // states [32w, 32w+32)
        const int g = rowid & 3, s = rowid >> 2;  // pre[4s+g] layout
        const int rg = g * DM + 32 * w + s;       // row in Whh0 / xg column
        uint4 wq[16];
#pragma unroll
        for (int j = 0; j < 16; j++) {
            const float4* p = (const float4*)(Whh0 + (size_t)rg * DM + 8 * c + 64 * j);
            float4 a = p[0], b = p[1];
            wq[j].x = pk2_(a.x, a.y); wq[j].y = pk2_(a.z, a.w);
            wq[j].z = pk2_(b.x, b.y); wq[j].w = pk2_(b.z, b.w);
        }
        const bool stg = (tid >= 64 && tid < 320);  // stagers: waves 1-4
        const int  slot = tid - 64;                 // u64 slot 0..255
        const bool ldr = (c == 0);                  // row leader
        const bool pub = (tid < 32);                // wave-0 publisher lanes
        float c0 = 0.f, h0v = 0.f;

        for (int t = 0; t < T_SEQ; t++) {
            const int par = t & 1;
            float xgv = 0.f;
            if (ldr) xgv = xg[(size_t)t * G4 + rg];   // RT hides under stage+B1

            if (t == 0) {
                if (stg) ((u64*)&h0st[0][0])[slot] = 0ull;
            } else if (stg) {
                PAUSE(S_RING);            // silent visibility wait
                const u64* hp = (const u64*)(h0h + (size_t)(t - 1) * DM) + slot;
                u64 v;
                for (;;) {
                    v = __hip_atomic_load(hp, __ATOMIC_RELAXED, __HIP_MEMORY_SCOPE_AGENT);
                    if (!has_sent_(v)) break;
                    PAUSE(S_RETRY);       // paced fallback, never unpaced
                }
                ((u64*)&h0st[par][0])[slot] = v;
            }
            __syncthreads();              // B1: h0st[par] staged

            // dot: row rg · h0(t-1); weights VGPR, vector from LDS
            const uint4* hb = &h0st[par][0];
            float acc = 0.f;
#pragma unroll
            for (int j = 0; j < 16; j++)
                acc = dot8a_(wq[j], hb[c + 8 * j], acc);
            acc += __shfl_xor(acc, 1, 64);
            acc += __shfl_xor(acc, 2, 64);
            acc += __shfl_xor(acc, 4, 64);
            if (ldr) pre[rowid] = acc + xgv;
            __syncthreads();              // B2: pre[] complete

            if (pub) {                    // wave-0 lane tid = state tid
                float4 p4 = *(const float4*)&pre[4 * tid];   // i,f,g,o preacts
                float i_ = sigmoidf_(p4.x), f_ = sigmoidf_(p4.y);
                float g_ = tanhf_(p4.z),   o_ = sigmoidf_(p4.w);
                c0  = f_ * c0 + i_ * g_;
                h0v = o_ * tanhf_(c0);
                u32 q = pk2_(h0v, h0v);   // RTZ f16
                // 32 consecutive lanes -> ONE coalesced 64B line store
                __hip_atomic_store(h0h + (size_t)t * DM + 32 * w + tid,
                                   (u16)(q & 0xFFFFu),
                                   __ATOMIC_RELAXED, __HIP_MEMORY_SCOPE_AGENT);
            }
        }
    } else {
        // =============== Layer-1: 64 WGs x 16 states ===============
        const int u = blockIdx.x - 32;              // states [16u, 16u+16)
        const int g = rowid & 3;                    // gate
        const int m = (rowid >> 2) & 1;             // 0=Wih1(h0), 1=Whh1(h1)
        const int s = rowid >> 3;                   // state 0..15
        const float* WB = m ? Whh1 : Wih1;
        const int rg = g * DM + 16 * u + s;         // row within matrix
        uint4 wq[16];
#pragma unroll
        for (int j = 0; j < 16; j++) {
            const float4* p = (const float4*)(WB + (size_t)rg * DM + 8 * c + 64 * j);
            float4 a = p[0], b = p[1];
            wq[j].x = pk2_(a.x, a.y); wq[j].y = pk2_(a.z, a.w);
            wq[j].z = pk2_(b.x, b.y); wq[j].w = pk2_(b.z, b.w);
        }
        float bsum[4] = {0.f, 0.f, 0.f, 0.f};
        if (tid < 16) {
#pragma unroll
            for (int gg = 0; gg < 4; gg++)
                bsum[gg] = bih1[gg * DM + 16 * u + tid] + bhh1[gg * DM + 16 * u + tid];
        }
        const bool st0 = (tid >= 64 && tid < 320);   // h0 stagers
        const int  sl0 = tid - 64;
        const bool st1 = (tid >= 320 && tid < 576);  // h1 stagers
        const int  sl1 = tid - 320;
        const bool ldr = (c == 0);
        const bool pub = (tid < 16);
        float c1 = 0.f, h1v = 0.f;

        for (int t = 0; t < T_SEQ; t++) {
            const int par = t & 1;

            // h0(t): load-first (L0 leads in steady state), paced catch-up.
            if (st0) {
                const u64* hp = (const u64*)(h0h + (size_t)t * DM) + sl0;
                u64 v = __hip_atomic_load(hp, __ATOMIC_RELAXED, __HIP_MEMORY_SCOPE_AGENT);
                while (has_sent_(v)) {
                    PAUSE(S_HIST);
                    v = __hip_atomic_load(hp, __ATOMIC_RELAXED, __HIP_MEMORY_SCOPE_AGENT);
                }
                ((u64*)&h0st[par][0])[sl0] = v;
            }
            // h1(t-1): zero-gap self-ring -> sleep-first, one burst, paced.
            if (t == 0) {
                if (st1) ((u64*)&h1st[0][0])[sl1] = 0ull;
            } else if (st1) {
                PAUSE(S_RING);
                const u64* hp = (const u64*)(h1h + (size_t)(t - 1) * DM) + sl1;
                u64 v;
                for (;;) {
                    v = __hip_atomic_load(hp, __ATOMIC_RELAXED, __HIP_MEMORY_SCOPE_AGENT);
                    if (!has_sent_(v)) break;
                    PAUSE(S_RETRY);
                }
                ((u64*)&h1st[par][0])[sl1] = v;
            }
            __syncthreads();              // B1: both vectors staged

            const uint4* hb = m ? &h1st[par][0] : &h0st[par][0];
            float acc = 0.f;
#pragma unroll
            for (int j = 0; j < 16; j++)
                acc = dot8a_(wq[j], hb[c + 8 * j], acc);
            acc += __shfl_xor(acc, 1, 64);
            acc += __shfl_xor(acc, 2, 64);
            acc += __shfl_xor(acc, 4, 64);
            if (ldr) pre[rowid] = acc;    // pre[8s + 4m + g]
            __syncthreads();              // B2: pre[] complete

            if (pub) {                    // wave-0 lane tid = state tid
                float4 pa = *(const float4*)&pre[8 * tid];       // Wih1 part
                float4 pb = *(const float4*)&pre[8 * tid + 4];   // Whh1 part
                float pi = pa.x + pb.x + bsum[0];
                float pf = pa.y + pb.y + bsum[1];
                float pg = pa.z + pb.z + bsum[2];
                float po = pa.w + pb.w + bsum[3];
                float i_ = sigmoidf_(pi), f_ = sigmoidf_(pf);
                float g_ = tanhf_(pg),    o_ = sigmoidf_(po);
                c1  = f_ * c1 + i_ * g_;
                h1v = o_ * tanhf_(c1);
                u32 q = pk2_(h1v, h1v);
                // 16 consecutive lanes -> ONE coalesced 32B store
                __hip_atomic_store(h1h + (size_t)t * DM + 16 * u + tid,
                                   (u16)(q & 0xFFFFu),
                                   __ATOMIC_RELAXED, __HIP_MEMORY_SCOPE_AGENT);
            }
            // Hazards: h0st/h1st[par] written pre-B1(t), read (dot) between
            // B1(t) and B2(t); next same-parity write pre-B1(t+2) is after
            // B2(t+1) -> >=2 barriers separate. pre[] write(t+1) is post-
            // B1(t+1), which wave 0 only passes after its post-B2(t) reads.
        }
        if (pub) out[16 * u + tid] = lrelu_(h1v);   // h1[T-1]
    }
}

// ---------------------------------------------------------------------------
extern "C" void kernel_launch(void* const* d_in, const int* in_sizes, int n_in,
                              void* d_out, int out_size, void* d_ws, size_t ws_size,
                              hipStream_t stream) {
    const float* inp = (const float*)d_in[0];   // 4096 x 64
    const float* W1  = (const float*)d_in[1];   // 1024 x 64
    const float* b1  = (const float*)d_in[2];   // 1024
    const float* Wih = (const float*)d_in[3];   // 2 x 4096 x 1024
    const float* Whh = (const float*)d_in[4];   // 2 x 4096 x 1024
    const float* bih = (const float*)d_in[5];   // 2 x 4096
    const float* bhh = (const float*)d_in[6];   // 2 x 4096
    float* out = (float*)d_out;                 // 1024

    // workspace layout:
    //   x: 4096*1024 f32 (16 MB; K1 out, K2 in) -> dead after K2, REUSED as
    //      h0h (8 MB f16) + h1h (8 MB f16) sentinel histories
    //   xg: 4096*4096 f32 (64 MB)
    float* x   = (float*)d_ws;
    float* xg  = x + (size_t)T_SEQ * DM;
    u16*   h0h = (u16*)d_ws;
    u16*   h1h = (u16*)d_ws + (size_t)T_SEQ * DM;
    (void)in_sizes; (void)n_in; (void)out_size; (void)ws_size;

    // Phase 1: input projection
    k_input<<<dim3(T_SEQ), dim3(256), 0, stream>>>(inp, W1, b1, x);

    // Phase 2: xg = x @ Wih0^T + (bih0+bhh0)
    k_gemm<<<dim3(32, 32), dim3(256), 0, stream>>>(x, Wih, bih, bhh, xg);

    // Phase 2b: x is dead -> sentinel-clear both histories (16 MB)
    k_clear<<<dim3(4096), dim3(256), 0, stream>>>((u32*)d_ws);

    // Phase 3: coarse-granularity decoupled scans (32 L0 + 64 L1 WGs)
    k_scan<<<dim3(96), dim3(1024), 0, stream>>>(
        xg, Wih + LSTRIDE_W, Whh, Whh + LSTRIDE_W,
        bih + LSTRIDE_B, bhh + LSTRIDE_B, h0h, h1h, out);
}

// Round 14
// 8309.179 us; speedup vs baseline: 1.0313x; 1.0313x over previous
//
#include <hip/hip_runtime.h>
#include <hip/hip_fp16.h>
#include <math.h>

// Problem dims (fixed)
#define T_SEQ 4096
#define DIN   64
#define DM    1024
#define G4    4096              // 4*DM gate rows
#define LSTRIDE_W ((size_t)G4 * DM)   // per-layer Wih/Whh stride
#define LSTRIDE_B ((size_t)G4)        // per-layer bias stride

#define SENT16 0xDEADu          // f16 sentinel: |h|<=1 never encodes 0xDEAD
#define SENT32 0xDEADDEADu

// Timed waits — FINAL. Full S_RING response curve measured:
//   12: chronic miss + perturbation (8.90ms); 22: best (8.01-8.20ms);
//   25: equal within noise; 28: clean but over-waits (8.21-8.25ms);
//   40: slow. Plateau 22-25: sleep trades vs retry ~1:1 (broad visibility
//   tail straddles the window). 22 chosen (best measured total).
// Session lessons:
//  R15: fixed pacing only (closed-loop adaptive pacing diverges).
//  R18: sample ONCE; early probes miss and perturb the propagation.
//  R19: period scales with PUBLISHER COUNT (32 L0 / 64 L1 is optimal).
//  R20: publisher's post-B2 tail is free (hidden under stagers' sleep).
//  Floor: period ~= visibility (~2100-2500cy) + load RT (~700) + serial
//  compute segment (~2000) -> ~8.0ms scan. Latency-bound, not BW/compute.
#define S_RING  22              // s_sleep(22) ~1408 cy: ring visibility wait
#define S_RETRY 6               // ~384 cy paced retry
#define S_HIST  8               // ~512 cy: L1 catch-up when L0 is behind

typedef unsigned long long u64;
typedef unsigned int u32;
typedef unsigned short u16;

// sleep + compiler memory fence (prevent hoisting atomic loads above it)
#define PAUSE(n) do { __builtin_amdgcn_s_sleep(n); asm volatile("" ::: "memory"); } while (0)

__device__ __forceinline__ float sigmoidf_(float x) {
    return 1.0f / (1.0f + __expf(-x));
}
__device__ __forceinline__ float tanhf_(float x) {
    float ax = fabsf(x);
    float e  = __expf(-2.0f * ax);
    float t  = (1.0f - e) / (1.0f + e);
    return copysignf(t, x);
}
__device__ __forceinline__ float lrelu_(float x) {
    return x > 0.0f ? x : 0.01f * x;
}

// pack two fp32 -> one u32 of two f16 (v_cvt_pkrtz_f16_f32)
__device__ __forceinline__ u32 pk2_(float x, float y) {
    typedef __fp16 hv2 __attribute__((ext_vector_type(2)));
    union { hv2 h; u32 u; } c;
    c.h = __builtin_amdgcn_cvt_pkrtz(x, y);
    return c.u;
}
// fused f16-pair dot-accumulate: acc += a.x*b.x + a.y*b.y
#if __has_builtin(__builtin_amdgcn_fdot2)
__device__ __forceinline__ float d2a_(u32 a, u32 b, float acc) {
    typedef __fp16 hv2 __attribute__((ext_vector_type(2)));
    union { u32 u; hv2 h; } ua, ub;
    ua.u = a; ub.u = b;
    return __builtin_amdgcn_fdot2(ua.h, ub.h, acc, false);
}
#else
__device__ __forceinline__ float d2a_(u32 a, u32 b, float acc) {
    union { u32 u; __half2 h; } ua, ub;
    ua.u = a; ub.u = b;
    float2 fa = __half22float2(ua.h);
    float2 fb = __half22float2(ub.h);
    return acc + fa.x * fb.x + fa.y * fb.y;
}
#endif
__device__ __forceinline__ float dot8a_(uint4 q, uint4 h, float acc) {
    acc = d2a_(q.x, h.x, acc);
    acc = d2a_(q.y, h.y, acc);
    acc = d2a_(q.z, h.z, acc);
    acc = d2a_(q.w, h.w, acc);
    return acc;
}
// any of the four f16 fields still the sentinel?
__device__ __forceinline__ bool has_sent_(u64 v) {
    return (((u32)v & 0xFFFFu) == SENT16) | ((((u32)v >> 16)) == SENT16) |
           (((u32)(v >> 32) & 0xFFFFu) == SENT16) | (((u32)(v >> 48)) == SENT16);
}

// ---------------------------------------------------------------------------
// K1: x[t,d] = leaky_relu(sum_k inp[t,k]*W1[d,k] + b1[d]);  grid=4096, block=256
// ---------------------------------------------------------------------------
__global__ __launch_bounds__(256) void k_input(const float* __restrict__ inp,
                                               const float* __restrict__ W1,
                                               const float* __restrict__ b1,
                                               float* __restrict__ x) {
    __shared__ float s_in[DIN];
    const int t   = blockIdx.x;
    const int tid = threadIdx.x;
    if (tid < DIN) s_in[tid] = inp[(size_t)t * DIN + tid];
    __syncthreads();
#pragma unroll
    for (int q = 0; q < 4; q++) {
        const int d = tid + q * 256;
        const float4* wr = (const float4*)(W1 + (size_t)d * DIN);
        float acc = 0.0f;
#pragma unroll
        for (int e = 0; e < 16; e++) {
            float4 w = wr[e];
            acc += w.x * s_in[e * 4 + 0] + w.y * s_in[e * 4 + 1] +
                   w.z * s_in[e * 4 + 2] + w.w * s_in[e * 4 + 3];
        }
        acc += b1[d];
        x[(size_t)t * DM + d] = lrelu_(acc);
    }
}

// ---------------------------------------------------------------------------
// K2: xg[m,n] = sum_k x[m,k]*Wih0[n,k] + (bih0[n]+bhh0[n])
// 128x128 tile, BK=16, 256 threads, 8x8 per thread.
// ---------------------------------------------------------------------------
__global__ __launch_bounds__(256) void k_gemm(const float* __restrict__ A,
                                              const float* __restrict__ B,
                                              const float* __restrict__ bih,
                                              const float* __restrict__ bhh,
                                              float* __restrict__ C) {
    const int K = DM;
    __shared__ float As[16][132];
    __shared__ float Bs[16][132];
    const int tid = threadIdx.x;
    const int m0 = blockIdx.y * 128, n0 = blockIdx.x * 128;
    const int tx = tid & 15, ty = tid >> 4;
    const int lr = tid >> 1;
    const int lc = (tid & 1) * 8;

    float acc[8][8] = {};
    const float4* ag = (const float4*)(A + (size_t)(m0 + lr) * K + lc);
    const float4* bg = (const float4*)(B + (size_t)(n0 + lr) * K + lc);

    for (int k0 = 0; k0 < K; k0 += 16) {
        float4 a0 = ag[0], a1 = ag[1];
        float4 b0 = bg[0], b1v = bg[1];
        ag += 4; bg += 4;
        __syncthreads();
        As[lc + 0][lr] = a0.x; As[lc + 1][lr] = a0.y; As[lc + 2][lr] = a0.z; As[lc + 3][lr] = a0.w;
        As[lc + 4][lr] = a1.x; As[lc + 5][lr] = a1.y; As[lc + 6][lr] = a1.z; As[lc + 7][lr] = a1.w;
        Bs[lc + 0][lr] = b0.x; Bs[lc + 1][lr] = b0.y; Bs[lc + 2][lr] = b0.z; Bs[lc + 3][lr] = b0.w;
        Bs[lc + 4][lr] = b1v.x; Bs[lc + 5][lr] = b1v.y; Bs[lc + 6][lr] = b1v.z; Bs[lc + 7][lr] = b1v.w;
        __syncthreads();
#pragma unroll
        for (int k = 0; k < 16; k++) {
            float a[8], b[8];
            *(float4*)&a[0] = *(const float4*)&As[k][ty * 8 + 0];
            *(float4*)&a[4] = *(const float4*)&As[k][ty * 8 + 4];
            *(float4*)&b[0] = *(const float4*)&Bs[k][tx * 8 + 0];
            *(float4*)&b[4] = *(const float4*)&Bs[k][tx * 8 + 4];
#pragma unroll
            for (int i = 0; i < 8; i++)
#pragma unroll
                for (int j = 0; j < 8; j++)
                    acc[i][j] += a[i] * b[j];
        }
    }
    float bj[8];
#pragma unroll
    for (int j = 0; j < 8; j++) {
        int n = n0 + tx * 8 + j;
        bj[j] = bih[n] + bhh[n];
    }
#pragma unroll
    for (int i = 0; i < 8; i++) {
        float4 v0, v1;
        v0.x = acc[i][0] + bj[0]; v0.y = acc[i][1] + bj[1];
        v0.z = acc[i][2] + bj[2]; v0.w = acc[i][3] + bj[3];
        v1.x = acc[i][4] + bj[4]; v1.y = acc[i][5] + bj[5];
        v1.z = acc[i][6] + bj[6]; v1.w = acc[i][7] + bj[7];
        float* cp = C + (size_t)(m0 + ty * 8 + i) * G4 + n0 + tx * 8;
        *(float4*)(cp + 0) = v0;
        *(float4*)(cp + 4) = v1;
    }
}

// ---------------------------------------------------------------------------
// K2b: sentinel-clear BOTH f16 histories (16 MB over the dead x buffer).
// ---------------------------------------------------------------------------
__global__ __launch_bounds__(256) void k_clear(u32* __restrict__ p) {
    uint4 v; v.x = SENT32; v.y = SENT32; v.z = SENT32; v.w = SENT32;
    ((uint4*)p)[(size_t)blockIdx.x * 256 + threadIdx.x] = v;
}

// ---------------------------------------------------------------------------
// K3: FINAL = R17 topology + S_RING=22 (R22, best measured: 8.44ms total,
// -25% vs session baseline 11.26ms).
//
// Structure: decoupled layer scans over f16 sentinel histories.
//   - 32 L0 WGs x 32 states, 64 L1 WGs x 16 states, 1024 threads each.
//   - Publish: all states of a WG on wave-0 lanes -> ONE coalesced 64B/32B
//     store per step (32/64 publishers; R19: fewer, coalesced publishers
//     beat more CUs). Publisher activations stay post-B2 (sleep-hidden).
//   - Consume: 256 stager threads load producer rows as coalesced u64s;
//     zero-gap rings: silent sleep(1408cy) -> sample ONCE -> paced retries.
//     L1's h0 read is load-first (L0 structurally leads) + paced catch-up.
//   - Dot: 128 rows/WG, 8 threads/row, weights in 64 VGPRs (f16 pairs),
//     k-interleaved LDS reads (conflict-free), shfl_xor reduce.
// Floor (measured, 13 rounds): period ~4700cy = visibility ~2100-2500 +
// load RT ~700 + serial dot/barrier segment ~2000. Latency-bound; HBM and
// VALU both <30% — no counter headroom convertible by any tested mechanism.
// ---------------------------------------------------------------------------
__global__ __launch_bounds__(1024, 1) void k_scan(
        const float* __restrict__ xg,     // T x 4096 layer-0 preacts
        const float* __restrict__ Wih1,
        const float* __restrict__ Whh0,
        const float* __restrict__ Whh1,
        const float* __restrict__ bih1,
        const float* __restrict__ bhh1,
        u16* h0h,                         // [T][1024] f16 h0 history (sentinel)
        u16* h1h,                         // [T][1024] f16 h1 history (sentinel)
        float* __restrict__ out) {
    const int tid   = threadIdx.x;
    const int rowid = tid >> 3;           // 0..127: row handled by this thread
    const int c     = tid & 7;            // k-chunk within row
    const bool isL0 = (blockIdx.x < 32);

    __shared__ uint4 h0st[2][128];        // staged h0 row (f16), parity dbuf
    __shared__ uint4 h1st[2][128];        // staged h1 row (f16), parity dbuf
    __shared__ __align__(16) float pre[128];  // row preacts for gate gather

    if (isL0) {
        // =============== Layer-0: 32 WGs x 32 states ===============
        const int w = blockIdx.x;                 // states [32w, 32w+32)
        const int g = rowid & 3, s = rowid >> 2;  // pre[4s+g] layout
        const int rg = g * DM + 32 * w + s;       // row in Whh0 / xg column
        uint4 wq[16];
#pragma unroll
        for (int j = 0; j < 16; j++) {
            const float4* p = (const float4*)(Whh0 + (size_t)rg * DM + 8 * c + 64 * j);
            float4 a = p[0], b = p[1];
            wq[j].x = pk2_(a.x, a.y); wq[j].y = pk2_(a.z, a.w);
            wq[j].z = pk2_(b.x, b.y); wq[j].w = pk2_(b.z, b.w);
        }
        const bool stg = (tid >= 64 && tid < 320);  // stagers: waves 1-4
        const int  slot = tid - 64;                 // u64 slot 0..255
        const bool ldr = (c == 0);                  // row leader
        const bool pub = (tid < 32);                // wave-0 publisher lanes
        float c0 = 0.f, h0v = 0.f;

        for (int t = 0; t < T_SEQ; t++) {
            const int par = t & 1;
            float xgv = 0.f;
            if (ldr) xgv = xg[(size_t)t * G4 + rg];   // RT hides under stage+B1

            if (t == 0) {
                if (stg) ((u64*)&h0st[0][0])[slot] = 0ull;
            } else if (stg) {
                PAUSE(S_RING);            // silent visibility wait
                const u64* hp = (const u64*)(h0h + (size_t)(t - 1) * DM) + slot;
                u64 v;
                for (;;) {
                    v = __hip_atomic_load(hp, __ATOMIC_RELAXED, __HIP_MEMORY_SCOPE_AGENT);
                    if (!has_sent_(v)) break;
                    PAUSE(S_RETRY);       // paced fallback, never unpaced
                }
                ((u64*)&h0st[par][0])[slot] = v;
            }
            __syncthreads();              // B1: h0st[par] staged

            // dot: row rg · h0(t-1); weights VGPR, vector from LDS
            const uint4* hb = &h0st[par][0];
            float acc = 0.f;
#pragma unroll
            for (int j = 0; j < 16; j++)
                acc = dot8a_(wq[j], hb[c + 8 * j], acc);
            acc += __shfl_xor(acc, 1, 64);
            acc += __shfl_xor(acc, 2, 64);
            acc += __shfl_xor(acc, 4, 64);
            if (ldr) pre[rowid] = acc + xgv;
            __syncthreads();              // B2: pre[] complete

            if (pub) {                    // wave-0 lane tid = state tid
                float4 p4 = *(const float4*)&pre[4 * tid];   // i,f,g,o preacts
                float i_ = sigmoidf_(p4.x), f_ = sigmoidf_(p4.y);
                float g_ = tanhf_(p4.z),   o_ = sigmoidf_(p4.w);
                c0  = f_ * c0 + i_ * g_;
                h0v = o_ * tanhf_(c0);
                u32 q = pk2_(h0v, h0v);   // RTZ f16
                // 32 consecutive lanes -> ONE coalesced 64B line store
                __hip_atomic_store(h0h + (size_t)t * DM + 32 * w + tid,
                                   (u16)(q & 0xFFFFu),
                                   __ATOMIC_RELAXED, __HIP_MEMORY_SCOPE_AGENT);
            }
        }
    } else {
        // =============== Layer-1: 64 WGs x 16 states ===============
        const int u = blockIdx.x - 32;              // states [16u, 16u+16)
        const int g = rowid & 3;                    // gate
        const int m = (rowid >> 2) & 1;             // 0=Wih1(h0), 1=Whh1(h1)
        const int s = rowid >> 3;                   // state 0..15
        const float* WB = m ? Whh1 : Wih1;
        const int rg = g * DM + 16 * u + s;         // row within matrix
        uint4 wq[16];
#pragma unroll
        for (int j = 0; j < 16; j++) {
            const float4* p = (const float4*)(WB + (size_t)rg * DM + 8 * c + 64 * j);
            float4 a = p[0], b = p[1];
            wq[j].x = pk2_(a.x, a.y); wq[j].y = pk2_(a.z, a.w);
            wq[j].z = pk2_(b.x, b.y); wq[j].w = pk2_(b.z, b.w);
        }
        float bsum[4] = {0.f, 0.f, 0.f, 0.f};
        if (tid < 16) {
#pragma unroll
            for (int gg = 0; gg < 4; gg++)
                bsum[gg] = bih1[gg * DM + 16 * u + tid] + bhh1[gg * DM + 16 * u + tid];
        }
        const bool st0 = (tid >= 64 && tid < 320);   // h0 stagers
        const int  sl0 = tid - 64;
        const bool st1 = (tid >= 320 && tid < 576);  // h1 stagers
        const int  sl1 = tid - 320;
        const bool ldr = (c == 0);
        const bool pub = (tid < 16);
        float c1 = 0.f, h1v = 0.f;

        for (int t = 0; t < T_SEQ; t++) {
            const int par = t & 1;

            // h0(t): load-first (L0 leads in steady state), paced catch-up.
            if (st0) {
                const u64* hp = (const u64*)(h0h + (size_t)t * DM) + sl0;
                u64 v = __hip_atomic_load(hp, __ATOMIC_RELAXED, __HIP_MEMORY_SCOPE_AGENT);
                while (has_sent_(v)) {
                    PAUSE(S_HIST);
                    v = __hip_atomic_load(hp, __ATOMIC_RELAXED, __HIP_MEMORY_SCOPE_AGENT);
                }
                ((u64*)&h0st[par][0])[sl0] = v;
            }
            // h1(t-1): zero-gap self-ring -> sleep-first, one burst, paced.
            if (t == 0) {
                if (st1) ((u64*)&h1st[0][0])[sl1] = 0ull;
            } else if (st1) {
                PAUSE(S_RING);
                const u64* hp = (const u64*)(h1h + (size_t)(t - 1) * DM) + sl1;
                u64 v;
                for (;;) {
                    v = __hip_atomic_load(hp, __ATOMIC_RELAXED, __HIP_MEMORY_SCOPE_AGENT);
                    if (!has_sent_(v)) break;
                    PAUSE(S_RETRY);
                }
                ((u64*)&h1st[par][0])[sl1] = v;
            }
            __syncthreads();              // B1: both vectors staged

            const uint4* hb = m ? &h1st[par][0] : &h0st[par][0];
            float acc = 0.f;
#pragma unroll
            for (int j = 0; j < 16; j++)
                acc = dot8a_(wq[j], hb[c + 8 * j], acc);
            acc += __shfl_xor(acc, 1, 64);
            acc += __shfl_xor(acc, 2, 64);
            acc += __shfl_xor(acc, 4, 64);
            if (ldr) pre[rowid] = acc;    // pre[8s + 4m + g]
            __syncthreads();              // B2: pre[] complete

            if (pub) {                    // wave-0 lane tid = state tid
                float4 pa = *(const float4*)&pre[8 * tid];       // Wih1 part
                float4 pb = *(const float4*)&pre[8 * tid + 4];   // Whh1 part
                float pi = pa.x + pb.x + bsum[0];
                float pf = pa.y + pb.y + bsum[1];
                float pg = pa.z + pb.z + bsum[2];
                float po = pa.w + pb.w + bsum[3];
                float i_ = sigmoidf_(pi), f_ = sigmoidf_(pf);
                float g_ = tanhf_(pg),    o_ = sigmoidf_(po);
                c1  = f_ * c1 + i_ * g_;
                h1v = o_ * tanhf_(c1);
                u32 q = pk2_(h1v, h1v);
                // 16 consecutive lanes -> ONE coalesced 32B store
                __hip_atomic_store(h1h + (size_t)t * DM + 16 * u + tid,
                                   (u16)(q & 0xFFFFu),
                                   __ATOMIC_RELAXED, __HIP_MEMORY_SCOPE_AGENT);
            }
            // Hazards: h0st/h1st[par] written pre-B1(t), read (dot) between
            // B1(t) and B2(t); next same-parity write pre-B1(t+2) is after
            // B2(t+1) -> >=2 barriers separate. pre[] write(t+1) is post-
            // B1(t+1), which wave 0 only passes after its post-B2(t) reads.
        }
        if (pub) out[16 * u + tid] = lrelu_(h1v);   // h1[T-1]
    }
}

// ---------------------------------------------------------------------------
extern "C" void kernel_launch(void* const* d_in, const int* in_sizes, int n_in,
                              void* d_out, int out_size, void* d_ws, size_t ws_size,
                              hipStream_t stream) {
    const float* inp = (const float*)d_in[0];   // 4096 x 64
    const float* W1  = (const float*)d_in[1];   // 1024 x 64
    const float* b1  = (const float*)d_in[2];   // 1024
    const float* Wih = (const float*)d_in[3];   // 2 x 4096 x 1024
    const float* Whh = (const float*)d_in[4];   // 2 x 4096 x 1024
    const float* bih = (const float*)d_in[5];   // 2 x 4096
    const float* bhh = (const float*)d_in[6];   // 2 x 4096
    float* out = (float*)d_out;                 // 1024

    // workspace layout:
    //   x: 4096*1024 f32 (16 MB; K1 out, K2 in) -> dead after K2, REUSED as
    //      h0h (8 MB f16) + h1h (8 MB f16) sentinel histories
    //   xg: 4096*4096 f32 (64 MB)
    float* x   = (float*)d_ws;
    float* xg  = x + (size_t)T_SEQ * DM;
    u16*   h0h = (u16*)d_ws;
    u16*   h1h = (u16*)d_ws + (size_t)T_SEQ * DM;
    (void)in_sizes; (void)n_in; (void)out_size; (void)ws_size;

    // Phase 1: input projection
    k_input<<<dim3(T_SEQ), dim3(256), 0, stream>>>(inp, W1, b1, x);

    // Phase 2: xg = x @ Wih0^T + (bih0+bhh0)
    k_gemm<<<dim3(32, 32), dim3(256), 0, stream>>>(x, Wih, bih, bhh, xg);

    // Phase 2b: x is dead -> sentinel-clear both histories (16 MB)
    k_clear<<<dim3(4096), dim3(256), 0, stream>>>((u32*)d_ws);

    // Phase 3: coarse-granularity decoupled scans (32 L0 + 64 L1 WGs)
    k_scan<<<dim3(96), dim3(1024), 0, stream>>>(
        xg, Wih + LSTRIDE_W, Whh, Whh + LSTRIDE_W,
        bih + LSTRIDE_B, bhh + LSTRIDE_B, h0h, h1h, out);
}